// Round 1
// baseline (620.047 us; speedup 1.0000x reference)
//
#include <hip/hip_runtime.h>

// Problem constants (fixed by setup_inputs)
#define BATCH 32
#define NSENS 8
#define NSAMP (BATCH * NSENS)   // 256 samples
#define IN_C 64
#define OUT_C 128
#define KW 5
#define RANK 8
#define T_IN 2048
#define T_OUT 1024
#define GROUPS 4
#define CPG (OUT_C / GROUPS)    // 32 channels per group
#define EPSV 1e-5f
#define M_DIM (IN_C * KW)       // 320 reduction length
#define WPB (OUT_C * M_DIM)     // 40960 weights per batch sample

// ---------------------------------------------------------------------------
// Kernel A: W_eff[b][co][ci][j] = conv_w[co][ci][j] + scale * sum_r B[b][co][r]*A[b][r][ci*5+j]
// ---------------------------------------------------------------------------
__global__ void build_weights(const float* __restrict__ A_flat,
                              const float* __restrict__ B_flat,
                              const float* __restrict__ conv_w,
                              const float* __restrict__ scale_p,
                              float* __restrict__ Weff) {
    int idx = blockIdx.x * 256 + threadIdx.x;
    if (idx >= BATCH * WPB) return;
    int b   = idx / WPB;
    int rem = idx - b * WPB;
    int co  = rem / M_DIM;
    int m   = rem - co * M_DIM;
    const float* Bp = B_flat + (size_t)b * OUT_C * RANK + co * RANK;
    const float* Ap = A_flat + (size_t)b * RANK * M_DIM + m;
    float d = 0.f;
#pragma unroll
    for (int rr = 0; rr < RANK; ++rr)
        d = fmaf(Bp[rr], Ap[rr * M_DIM], d);
    Weff[idx] = conv_w[rem] + scale_p[0] * d;
}

// ---------------------------------------------------------------------------
// Kernel B: fused conv1d(stride2,k5,pad2) + bias + ReLU + GroupNorm
// One block per (sample, group). 1024 threads; thread t owns output time t
// for all 32 channels of the group (accumulators in VGPRs). Weights are
// wave-uniform -> scalar loads. GroupNorm stats via block reduction.
// ---------------------------------------------------------------------------
__global__ __launch_bounds__(1024, 4)
void conv_gn(const float* __restrict__ x,
             const float* __restrict__ Weff,
             const float* __restrict__ conv_b,
             const float* __restrict__ gamma,
             const float* __restrict__ beta,
             float* __restrict__ out) {
    const int blk    = blockIdx.x;       // sample*4 + g
    const int sample = blk >> 2;
    const int g      = blk & 3;
    const int b      = sample >> 3;      // / NSENS
    const int t      = threadIdx.x;      // 0..1023

    const float* xs = x    + (size_t)sample * IN_C * T_IN;
    const float* Wg = Weff + (size_t)b * WPB + (size_t)g * CPG * M_DIM;

    float acc[CPG];
#pragma unroll
    for (int c = 0; c < CPG; ++c) acc[c] = 0.f;

    const int base = 2 * t - 2;
    // boundary predicates (only t==0 and t==1023 waves diverge)
    const bool v0 = (base     >= 0);
    const bool v1 = (base + 1 >= 0);
    const bool v4 = (base + 4 <  T_IN);

#pragma unroll 2
    for (int ci = 0; ci < IN_C; ++ci) {
        const float* xr = xs + ci * T_IN;
        float xv0 = v0 ? xr[base]     : 0.f;
        float xv1 = v1 ? xr[base + 1] : 0.f;
        float xv2 =      xr[base + 2];
        float xv3 =      xr[base + 3];
        float xv4 = v4 ? xr[base + 4] : 0.f;
        const float* wp = Wg + ci * KW;
#pragma unroll
        for (int co = 0; co < CPG; ++co) {
            const float* w = wp + co * M_DIM;  // uniform -> s_load
            float a = acc[co];
            a = fmaf(w[0], xv0, a);
            a = fmaf(w[1], xv1, a);
            a = fmaf(w[2], xv2, a);
            a = fmaf(w[3], xv3, a);
            a = fmaf(w[4], xv4, a);
            acc[co] = a;
        }
    }

    // bias + ReLU + local stats
    const int cbase = g * CPG;
    float s1 = 0.f, s2 = 0.f;
#pragma unroll
    for (int co = 0; co < CPG; ++co) {
        float v = acc[co] + conv_b[cbase + co];
        v = v > 0.f ? v : 0.f;
        s1 += v;
        s2 = fmaf(v, v, s2);
    }

    // block reduction over 16 waves
    __shared__ float redS[16];
    __shared__ float redQ[16];
    __shared__ float bc[2];
#pragma unroll
    for (int off = 32; off > 0; off >>= 1) {
        s1 += __shfl_down(s1, off);
        s2 += __shfl_down(s2, off);
    }
    const int lane = threadIdx.x & 63;
    const int wid  = threadIdx.x >> 6;
    if (lane == 0) { redS[wid] = s1; redQ[wid] = s2; }
    __syncthreads();
    if (wid == 0) {
        float a = (lane < 16) ? redS[lane] : 0.f;
        float q = (lane < 16) ? redQ[lane] : 0.f;
#pragma unroll
        for (int off = 8; off > 0; off >>= 1) {
            a += __shfl_down(a, off);
            q += __shfl_down(q, off);
        }
        if (lane == 0) {
            const float invN = 1.f / (float)(CPG * T_OUT);
            float mean = a * invN;
            float var  = q * invN - mean * mean;
            bc[0] = mean;
            bc[1] = rsqrtf(var + EPSV);
        }
    }
    __syncthreads();
    const float mean = bc[0];
    const float inv  = bc[1];

    float* op = out + ((size_t)sample * OUT_C + cbase) * T_OUT + t;
#pragma unroll
    for (int co = 0; co < CPG; ++co) {
        float v = acc[co] + conv_b[cbase + co];
        v = v > 0.f ? v : 0.f;
        float nv = (v - mean) * inv * gamma[cbase + co] + beta[cbase + co];
        op[(size_t)co * T_OUT] = nv;
    }
}

// ---------------------------------------------------------------------------
extern "C" void kernel_launch(void* const* d_in, const int* in_sizes, int n_in,
                              void* d_out, int out_size, void* d_ws, size_t ws_size,
                              hipStream_t stream) {
    const float* x       = (const float*)d_in[0];
    const float* A_flat  = (const float*)d_in[1];
    const float* B_flat  = (const float*)d_in[2];
    const float* conv_w  = (const float*)d_in[3];
    const float* conv_b  = (const float*)d_in[4];
    const float* gamma   = (const float*)d_in[5];
    const float* beta    = (const float*)d_in[6];
    const float* scale_p = (const float*)d_in[9];

    float* out  = (float*)d_out;
    float* Weff = (float*)d_ws;   // 32*128*320*4 = 5.24 MB

    {
        int total  = BATCH * WPB;
        int blocks = (total + 255) / 256;
        build_weights<<<blocks, 256, 0, stream>>>(A_flat, B_flat, conv_w, scale_p, Weff);
    }
    {
        dim3 grid(NSAMP * GROUPS);   // 1024 blocks
        dim3 block(1024);
        conv_gn<<<grid, block, 0, stream>>>(x, Weff, conv_b, gamma, beta, out);
    }
}

// Round 2
// 90.843 us; speedup vs baseline: 6.8255x; 6.8255x over previous
//
#include <hip/hip_runtime.h>

#define T_IN 2048
#define T_OUT 1024
#define NCOL 2052
#define PITCH 36      // shorts per LDS column (32 ci + 4 pad); 72 B, non-pow2
#define EPSV 1e-5f

typedef short bf16x8 __attribute__((ext_vector_type(8)));
typedef short bf16x4 __attribute__((ext_vector_type(4)));
typedef float f32x4  __attribute__((ext_vector_type(4)));

__device__ __forceinline__ short f2bf(float f){
  unsigned u = __float_as_uint(f);
  u += 0x7fff + ((u >> 16) & 1);     // RNE
  return (short)(u >> 16);
}

// ---------------------------------------------------------------------------
// Kernel A: Wb[b][j][co][ci] = bf16(conv_w[co][ci][j] + scale * (B@A)[b][co][ci*5+j])
// idx is output-linear -> coalesced 2B stores.
// ---------------------------------------------------------------------------
__global__ void build_weights(const float* __restrict__ A_flat,
                              const float* __restrict__ B_flat,
                              const float* __restrict__ conv_w,
                              const float* __restrict__ scale_p,
                              short* __restrict__ Wb){
  int idx = blockIdx.x * 256 + threadIdx.x;   // ((b*5+j)*128 + co)*64 + ci
  int ci = idx & 63;
  int co = (idx >> 6) & 127;
  int bj = idx >> 13;          // 0..159
  int b  = bj / 5;
  int j  = bj - 5 * b;
  int m  = ci * 5 + j;
  const float* Bp = B_flat + (b * 128 + co) * 8;
  const float* Ap = A_flat + b * 8 * 320 + m;
  float d = 0.f;
#pragma unroll
  for (int r = 0; r < 8; ++r) d = fmaf(Bp[r], Ap[r * 320], d);
  float w = conv_w[co * 320 + m] + scale_p[0] * d;
  Wb[idx] = f2bf(w);
}

// ---------------------------------------------------------------------------
// Kernel B: block = (sample, group). 8 waves x 64. Full t-range per block ->
// single-pass GroupNorm from registers. conv = sum over j of GEMM(K=ci).
// ---------------------------------------------------------------------------
__global__ __launch_bounds__(512, 2)
void conv_gn_mfma(const float* __restrict__ x,
                  const short* __restrict__ Wb,
                  const float* __restrict__ conv_b,
                  const float* __restrict__ gamma,
                  const float* __restrict__ beta,
                  float* __restrict__ out){
  __shared__ short xl[NCOL * PITCH];          // 147744 B: [col][ci_local]
  __shared__ float redS[8], redQ[8], bc2[2];

  const int bid    = blockIdx.x;
  const int sample = ((bid & 7) << 5) + (bid >> 5);  // same sample -> same XCD
  const int g      = (bid >> 3) & 3;
  const int b      = sample >> 3;
  const int tid    = threadIdx.x;
  const int lane   = tid & 63;
  const int wid    = tid >> 6;       // 0..7
  const int l16    = lane & 15;
  const int lk     = lane >> 4;      // 0..3 (k-group)
  const int t0w    = wid << 7;       // wave owns t in [t0w, t0w+128)

  f32x4 acc[2][8];
#pragma unroll
  for (int m2 = 0; m2 < 2; ++m2)
#pragma unroll
    for (int n = 0; n < 8; ++n) acc[m2][n] = (f32x4){0.f, 0.f, 0.f, 0.f};

  const size_t wb_base = (size_t)b * 5 * 128 * 64;

  for (int ch = 0; ch < 2; ++ch) {
    if (ch) __syncthreads();         // compute(ch=0) done before overwrite
    // ---- stage chunk: x[sample][ch*32 .. +32][0..2048) -> xl[col][ci], transposed+bf16
    {
      const float* xs = x + ((size_t)sample * 64 + ch * 32 + wid * 4) * T_IN;
      if (tid < 72) {                // zero pad cols 0,1 (x=-2,-1) and 2050,2051
        int cc = tid / 18, dw = tid % 18;
        int col = (cc < 2) ? cc : (2048 + cc);
        *(int*)((char*)xl + col * 72 + dw * 4) = 0;
      }
#pragma unroll 2
      for (int pass = 0; pass < 8; ++pass) {
        int cb = pass * 256 + lane * 4;              // x col base (16B aligned)
        const float4 v0 = *(const float4*)(xs + 0 * T_IN + cb);
        const float4 v1 = *(const float4*)(xs + 1 * T_IN + cb);
        const float4 v2 = *(const float4*)(xs + 2 * T_IN + cb);
        const float4 v3 = *(const float4*)(xs + 3 * T_IN + cb);
        bf16x4 p0 = {f2bf(v0.x), f2bf(v1.x), f2bf(v2.x), f2bf(v3.x)};
        bf16x4 p1 = {f2bf(v0.y), f2bf(v1.y), f2bf(v2.y), f2bf(v3.y)};
        bf16x4 p2 = {f2bf(v0.z), f2bf(v1.z), f2bf(v2.z), f2bf(v3.z)};
        bf16x4 p3 = {f2bf(v0.w), f2bf(v1.w), f2bf(v2.w), f2bf(v3.w)};
        short* dst = &xl[(cb + 2) * PITCH + wid * 4];    // byte: col*72 + wid*8
        *(bf16x4*)(dst)             = p0;
        *(bf16x4*)(dst + PITCH)     = p1;
        *(bf16x4*)(dst + 2 * PITCH) = p2;
        *(bf16x4*)(dst + 3 * PITCH) = p3;
      }
    }
    __syncthreads();
    // ---- compute: 5 taps x (K=32 over this chunk's ci) x 8 n-frags x 2 m-frags
#pragma unroll
    for (int j = 0; j < 5; ++j) {
      const short* apb = Wb + wb_base + ((size_t)j * 128 + g * 32) * 64 + ch * 32 + lk * 8;
      bf16x8 a0 = *(const bf16x8*)(apb + (size_t)(l16)      * 64);
      bf16x8 a1 = *(const bf16x8*)(apb + (size_t)(l16 + 16) * 64);
#pragma unroll
      for (int n = 0; n < 8; ++n) {
        int c = 2 * (t0w + n * 16 + l16) + j;        // LDS col (= x col + 2)
        const short* bp = &xl[c * PITCH + lk * 8];
        bf16x4 lo = *(const bf16x4*)bp;
        bf16x4 hi = *(const bf16x4*)(bp + 4);
        bf16x8 bfr = {lo[0], lo[1], lo[2], lo[3], hi[0], hi[1], hi[2], hi[3]};
        acc[0][n] = __builtin_amdgcn_mfma_f32_16x16x32_bf16(a0, bfr, acc[0][n], 0, 0, 0);
        acc[1][n] = __builtin_amdgcn_mfma_f32_16x16x32_bf16(a1, bfr, acc[1][n], 0, 0, 0);
      }
    }
  }

  // ---- epilogue: bias + ReLU + GroupNorm (stats over all 8 waves = 32co x 1024t)
  float cb_[2][4], ga_[2][4], be_[2][4];
#pragma unroll
  for (int m2 = 0; m2 < 2; ++m2)
#pragma unroll
    for (int r = 0; r < 4; ++r) {
      int co = g * 32 + m2 * 16 + lk * 4 + r;
      cb_[m2][r] = conv_b[co];
      ga_[m2][r] = gamma[co];
      be_[m2][r] = beta[co];
    }
  float s1 = 0.f, s2 = 0.f;
#pragma unroll
  for (int m2 = 0; m2 < 2; ++m2)
#pragma unroll
    for (int n = 0; n < 8; ++n)
#pragma unroll
      for (int r = 0; r < 4; ++r) {
        float v = acc[m2][n][r] + cb_[m2][r];
        v = v > 0.f ? v : 0.f;
        acc[m2][n][r] = v;
        s1 += v;
        s2 = fmaf(v, v, s2);
      }
#pragma unroll
  for (int off = 32; off; off >>= 1) {
    s1 += __shfl_down(s1, off);
    s2 += __shfl_down(s2, off);
  }
  if (lane == 0) { redS[wid] = s1; redQ[wid] = s2; }
  __syncthreads();
  if (tid == 0) {
    float a = 0.f, q = 0.f;
#pragma unroll
    for (int w = 0; w < 8; ++w) { a += redS[w]; q += redQ[w]; }
    float mean = a * (1.f / 32768.f);
    float var  = q * (1.f / 32768.f) - mean * mean;
    bc2[0] = mean;
    bc2[1] = rsqrtf(var + EPSV);
  }
  __syncthreads();
  const float mean = bc2[0], inv = bc2[1];
  float* ob = out + (size_t)sample * 128 * 1024;
#pragma unroll
  for (int m2 = 0; m2 < 2; ++m2)
#pragma unroll
    for (int r = 0; r < 4; ++r) {
      int co = g * 32 + m2 * 16 + lk * 4 + r;
      float aa = ga_[m2][r] * inv;
      float bb = be_[m2][r] - mean * aa;
      float* orow = ob + (size_t)co * 1024 + t0w + l16;
#pragma unroll
      for (int n = 0; n < 8; ++n)
        orow[n * 16] = acc[m2][n][r] * aa + bb;
    }
}

// ---------------------------------------------------------------------------
extern "C" void kernel_launch(void* const* d_in, const int* in_sizes, int n_in,
                              void* d_out, int out_size, void* d_ws, size_t ws_size,
                              hipStream_t stream) {
  const float* x       = (const float*)d_in[0];
  const float* A_flat  = (const float*)d_in[1];
  const float* B_flat  = (const float*)d_in[2];
  const float* conv_w  = (const float*)d_in[3];
  const float* conv_b  = (const float*)d_in[4];
  const float* gamma   = (const float*)d_in[5];
  const float* beta    = (const float*)d_in[6];
  const float* scale_p = (const float*)d_in[9];

  float* out = (float*)d_out;
  short* Wb  = (short*)d_ws;   // 32*5*128*64 bf16 = 2.62 MB

  build_weights<<<5120, 256, 0, stream>>>(A_flat, B_flat, conv_w, scale_p, Wb);
  conv_gn_mfma<<<1024, 512, 0, stream>>>(x, Wb, conv_b, gamma, beta, out);
}